// Round 14
// baseline (1922.390 us; speedup 1.0000x reference)
//
#include <hip/hip_runtime.h>

#define NPTS 2048
#define NB   16
#define WGS  1024    // threads per wg (16 waves), 1 wg/CU
#define ARRV 16      // wgs per batch = barrier arrivals

typedef float v2f __attribute__((ext_vector_type(2)));

// eps = 0.01, log-domain Sinkhorn in base-2. Duals PRE-SCALED by R and
// PRE-SHIFTED by owner's plane const: fs = fR + xw, gs = gR + yw.
constexpr float K_R       = 144.26950408889634f;     // log2(e)/eps
constexpr float K_TWO_R   = 288.53900817779268f;     // 2R
constexpr float K_INV2R   = 0.0034657359027997264f;  // 1/(2R)
constexpr float K_EPS_LN2 = 0.0069314718055994531f;  // 1/R

// exp2 poly (deg-5, r in [-0.5,0.5], rel err <= 2.4e-6)
constexpr float MG = 12582912.0f;   // 1.5 * 2^23
constexpr float C0 = 1.0f;
constexpr float C1 = 0.6931471805599453f;
constexpr float C2 = 0.2402265069591007f;
constexpr float C3 = 0.0555041086648216f;
constexpr float C4 = 0.0096181291076285f;
constexpr float C5 = 0.0013333558146428f;

__device__ __forceinline__ float fexp2(float x) { return __builtin_amdgcn_exp2f(x); }
__device__ __forceinline__ float flog2(float x) { return __builtin_amdgcn_logf(x); }

// packed poly exp2: 2 elements, VALU-only (v_pk_* + cvt + ldexp)
__device__ __forceinline__ v2f pexp2(v2f w) {
    const v2f mg = {MG, MG};
    v2f t  = w + mg;
    v2f kf = t - mg;
    v2f r  = w - kf;
    v2f p  = {C5, C5};
    const v2f c4 = {C4, C4}, c3 = {C3, C3}, c2 = {C2, C2},
              c1 = {C1, C1}, c0 = {C0, C0};
    p = p * r + c4;
    p = p * r + c3;
    p = p * r + c2;
    p = p * r + c1;
    p = p * r + c0;
    v2f e;
    e.x = ldexpf(p.x, (int)kf.x);
    e.y = ldexpf(p.y, (int)kf.y);
    return e;
}

__device__ __forceinline__ float aload(const float* p) {
    return __hip_atomic_load(p, __ATOMIC_RELAXED, __HIP_MEMORY_SCOPE_AGENT);
}
__device__ __forceinline__ v2f aload2(const float* p) {
    unsigned long long v = __hip_atomic_load((const unsigned long long*)p,
                           __ATOMIC_RELAXED, __HIP_MEMORY_SCOPE_AGENT);
    union { unsigned long long u; v2f f; } c; c.u = v; return c.f;
}
__device__ __forceinline__ void astore(float* p, float v) {
    __hip_atomic_store(p, v, __ATOMIC_RELAXED, __HIP_MEMORY_SCOPE_AGENT);
}

// ---------------------------------------------------------------- prep ------
// Packed: (p*2R, -|p|^2*R); g initialized PRE-SHIFTED: gs = yw.
__global__ __launch_bounds__(256) void prep_kernel(
    const float* __restrict__ x, const float* __restrict__ y,
    float4* __restrict__ px, float4* __restrict__ py, float* __restrict__ g)
{
    int idx = blockIdx.x * 256 + threadIdx.x;
    if (idx >= NB * NPTS) return;
    float x0 = x[idx*3+0], x1 = x[idx*3+1], x2 = x[idx*3+2];
    float xx = fmaf(x0,x0, fmaf(x1,x1, x2*x2));
    px[idx] = make_float4(x0*K_TWO_R, x1*K_TWO_R, x2*K_TWO_R, -xx*K_R);
    float y0 = y[idx*3+0], y1 = y[idx*3+1], y2 = y[idx*3+2];
    float yy = fmaf(y0,y0, fmaf(y1,y1, y2*y2));
    py[idx] = make_float4(y0*K_TWO_R, y1*K_TWO_R, y2*K_TWO_R, -yy*K_R);
    g[idx] = -yy*K_R;   // gs = yw
}

// --------------------------------------------------------- batch barrier ----
// Fence-free monotonic barrier (R9 protocol, verified absmax 0.0).
__device__ __forceinline__ void batch_barrier(unsigned* ctr, unsigned target) {
    __syncthreads();
    if (threadIdx.x == 0) {
        asm volatile("s_waitcnt vmcnt(0)" ::: "memory");
        __hip_atomic_fetch_add(ctr, 1u, __ATOMIC_RELAXED, __HIP_MEMORY_SCOPE_AGENT);
        while (__hip_atomic_load(ctr, __ATOMIC_RELAXED, __HIP_MEMORY_SCOPE_AGENT)
               < target)
            __builtin_amdgcn_s_sleep(1);
        asm volatile("" ::: "memory");
    }
    __syncthreads();
}

// ------------------------------------------------------- persistent core ----
// 256 wgs = 1/CU (LDS ~74 KB). 16 waves/wg, 8 rows/wave. SoA j-pair planes
// in LDS; packed-f32 inner loop + packed poly exp2 (no trans-pipe).
__global__ __launch_bounds__(1024) void sinkhorn_fused(
    const float4* __restrict__ px4, const float4* __restrict__ py4,
    float* __restrict__ f, float* __restrict__ g,
    unsigned* __restrict__ bar, float* __restrict__ out)
{
    __shared__ v2f vyx[1024], vyy[1024], vyz[1024], vyw[1024];  // Y*2R; yw (EMD)
    __shared__ v2f vxx[1024], vxy[1024], vxz[1024];             // X*2R
    __shared__ v2f vhw[1024];          // per-phase: staged pre-shifted duals
    __shared__ v2f rowp[1024];         // pre-broadcast row constants
    __shared__ float wsum[16];

    const int bid   = blockIdx.x;
    const int b     = bid >> 4;
    const int chunk = bid & 15;
    const int tid   = threadIdx.x;
    const int lane  = tid & 63;
    const int wid   = tid >> 6;           // 0..15
    const int row0  = chunk * 128 + wid * 8;

    const float4* pyb = py4 + b * NPTS;
    const float4* pxb = px4 + b * NPTS;
    float* fb = f + b * NPTS;
    float* gb = g + b * NPTS;
    unsigned* ctr = bar + b * 64;

    // ---- stage SoA planes (2048 elems, 1024 thr) ----
    #pragma unroll
    for (int i2 = 0; i2 < 2; ++i2) {
        int k = i2 * WGS + tid;
        float4 p = pyb[k];
        ((float*)vyx)[k] = p.x; ((float*)vyy)[k] = p.y;
        ((float*)vyz)[k] = p.z; ((float*)vyw)[k] = p.w;
        float4 q2 = pxb[k];
        ((float*)vxx)[k] = q2.x; ((float*)vxy)[k] = q2.y;
        ((float*)vxz)[k] = q2.z;
    }
    // ---- row constants, pre-broadcast into pairs (1 per thread) ----
    {
        int ph  = tid >> 9;                // 0: f-rows (x), 1: g-rows (y)
        int w16 = (tid >> 5) & 15;
        int r   = (tid >> 2) & 7;
        int cp  = tid & 3;
        float4 p = (ph ? pyb : pxb)[chunk * 128 + w16 * 8 + r];
        float v = (cp == 0) ? p.x * K_INV2R :
                  (cp == 1) ? p.y * K_INV2R :
                  (cp == 2) ? p.z * K_INV2R : p.w;
        v2f t; t.x = v; t.y = v;
        rowp[(ph * 16 + w16) * 32 + r * 4 + cp] = t;
    }

    // dual_out gets PRE-SHIFTED value: -11 - log2(s) + u0_row
    auto run_phase = [&](const v2f* PX, const v2f* PY, const v2f* PZ,
                         int ph, float* dual_out) {
        v2f rx2[8], ry2[8], rz2[8], u02[8];
        const v2f* rp = &rowp[(ph * 16 + wid) * 32];
        #pragma unroll
        for (int r = 0; r < 8; ++r) {
            rx2[r] = rp[r*4+0]; ry2[r] = rp[r*4+1];
            rz2[r] = rp[r*4+2]; u02[r] = rp[r*4+3];
        }
        v2f acc2[8];
        #pragma unroll
        for (int r = 0; r < 8; ++r) { acc2[r].x = 0.f; acc2[r].y = 0.f; }

        #pragma unroll 2
        for (int c = 0; c < 16; ++c) {
            int jp = c * 64 + lane;
            v2f X = PX[jp], Y = PY[jp], Z = PZ[jp], H = vhw[jp];
            #pragma unroll
            for (int r = 0; r < 8; ++r) {
                v2f w = Z * rz2[r] + (H + u02[r]);
                w = Y * ry2[r] + w;
                w = X * rx2[r] + w;
                acc2[r] += pexp2(w);
            }
        }

        float sv[8];
        #pragma unroll
        for (int r = 0; r < 8; ++r) {
            float s = acc2[r].x + acc2[r].y;
            #pragma unroll
            for (int off = 1; off < 64; off <<= 1)
                s += __shfl_xor(s, off, 64);
            sv[r] = s;
        }
        if (lane < 8) {
            float s = sv[0];
            #pragma unroll
            for (int r = 1; r < 8; ++r) s = (lane == r) ? sv[r] : s;
            float u0s = ((const float*)&rp[lane * 4 + 3])[0];
            astore(&dual_out[lane], -11.0f - flog2(s) + u0s);
        }
    };

    unsigned tgt = ARRV;
    for (int it = 0; it < 50; ++it) {
        // ---- f-update: stage gs (pure copy) ----
        vhw[tid] = aload2(&gb[2 * tid]);
        __syncthreads();
        run_phase(vyx, vyy, vyz, 0, &fb[row0]);
        batch_barrier(ctr, tgt); tgt += ARRV;

        // ---- g-update: stage fs ----
        vhw[tid] = aload2(&fb[2 * tid]);
        __syncthreads();
        run_phase(vxx, vxy, vxz, 1, &gb[row0]);
        batch_barrier(ctr, tgt); tgt += ARRV;
    }

    // ---- EMD: H = gs;  w = 2Rx.y + gs + xw;  CR = (H-YW) - w;  P=2^(w+fR) ----
    vhw[tid] = aload2(&gb[2 * tid]);
    const v2f* rpf = &rowp[wid * 32];   // ph=0 x-rows
    float fR[8];
    #pragma unroll
    for (int r = 0; r < 8; ++r) {
        float xw = ((const float*)&rpf[r * 4 + 3])[0];
        fR[r] = aload(&fb[row0 + r]) - xw;
    }
    __syncthreads();

    {
        v2f rx2[8], ry2[8], rz2[8], u02[8];
        #pragma unroll
        for (int r = 0; r < 8; ++r) {
            rx2[r] = rpf[r*4+0]; ry2[r] = rpf[r*4+1];
            rz2[r] = rpf[r*4+2]; u02[r] = rpf[r*4+3];
        }
        v2f accE; accE.x = 0.f; accE.y = 0.f;
        #pragma unroll 2
        for (int c = 0; c < 16; ++c) {
            int jp = c * 64 + lane;
            v2f X = vyx[jp], Y = vyy[jp], Z = vyz[jp];
            v2f H = vhw[jp], YW = vyw[jp];
            #pragma unroll
            for (int r = 0; r < 8; ++r) {
                v2f w = Z * rz2[r] + (H + u02[r]);
                w = Y * ry2[r] + w;
                w = X * rx2[r] + w;
                v2f cr = (H - YW) - w;
                v2f e;
                e.x = fexp2(w.x + fR[r]) * cr.x;
                e.y = fexp2(w.y + fR[r]) * cr.y;
                accE += e;
            }
        }
        float s = accE.x + accE.y;
        #pragma unroll
        for (int off = 1; off < 64; off <<= 1) s += __shfl_xor(s, off, 64);
        if (lane == 0) wsum[wid] = s;
        __syncthreads();
        if (tid == 0) {
            float t = 0.f;
            #pragma unroll
            for (int i2 = 0; i2 < 16; ++i2) t += wsum[i2];
            atomicAdd(&out[b], t * K_EPS_LN2);
        }
    }
}

// -------------------------------------------------------------- launch ------
extern "C" void kernel_launch(void* const* d_in, const int* in_sizes, int n_in,
                              void* d_out, int out_size, void* d_ws, size_t ws_size,
                              hipStream_t stream)
{
    const float* x = (const float*)d_in[0];
    const float* y = (const float*)d_in[1];
    float* out = (float*)d_out;

    char* ws = (char*)d_ws;
    float4*   px  = (float4*)(ws);
    float4*   py  = (float4*)(ws + (size_t)NB * NPTS * 16);
    float*    f   = (float*)  (ws + (size_t)NB * NPTS * 32);
    float*    g   = (float*)  (ws + (size_t)NB * NPTS * 32 + (size_t)NB * NPTS * 4);
    unsigned* bar = (unsigned*)(ws + (size_t)NB * NPTS * 32 + (size_t)NB * NPTS * 8);

    hipMemsetAsync(d_out, 0, (size_t)out_size * sizeof(float), stream);
    hipMemsetAsync(bar, 0, NB * 64 * sizeof(unsigned), stream);

    prep_kernel<<<(NB * NPTS + 255) / 256, 256, 0, stream>>>(x, y, px, py, g);
    sinkhorn_fused<<<NB * ARRV, WGS, 0, stream>>>(px, py, f, g, bar, out);
}

// Round 15
// 1335.331 us; speedup vs baseline: 1.4396x; 1.4396x over previous
//
#include <hip/hip_runtime.h>

#define NPTS 2048
#define NB   16
#define WGS  1024    // 16 waves, 1 wg/CU (LDS > 80 KB forces exclusivity)

typedef float v2f __attribute__((ext_vector_type(2)));

// eps = 0.01, log-domain Sinkhorn in base-2. Duals PRE-SCALED by R and
// PRE-SHIFTED by owner's plane const: fs = fR + xw, gs = gR + yw.
constexpr float K_R       = 144.26950408889634f;     // log2(e)/eps
constexpr float K_TWO_R   = 288.53900817779268f;     // 2R
constexpr float K_INV2R   = 0.0034657359027997264f;  // 1/(2R)
constexpr float K_EPS_LN2 = 0.0069314718055994531f;  // 1/R

__device__ __forceinline__ float fexp2(float x) { return __builtin_amdgcn_exp2f(x); }
__device__ __forceinline__ float flog2(float x) { return __builtin_amdgcn_logf(x); }

__device__ __forceinline__ float aload(const float* p) {
    return __hip_atomic_load(p, __ATOMIC_RELAXED, __HIP_MEMORY_SCOPE_AGENT);
}
__device__ __forceinline__ v2f aload2(const float* p) {
    unsigned long long v = __hip_atomic_load((const unsigned long long*)p,
                           __ATOMIC_RELAXED, __HIP_MEMORY_SCOPE_AGENT);
    union { unsigned long long u; v2f f; } c; c.u = v; return c.f;
}
__device__ __forceinline__ void astore(float* p, float v) {
    __hip_atomic_store(p, v, __ATOMIC_RELAXED, __HIP_MEMORY_SCOPE_AGENT);
}
__device__ __forceinline__ unsigned aloadu(const unsigned* p) {
    return __hip_atomic_load(p, __ATOMIC_RELAXED, __HIP_MEMORY_SCOPE_AGENT);
}
__device__ __forceinline__ void astoreu(unsigned* p, unsigned v) {
    __hip_atomic_store(p, v, __ATOMIC_RELAXED, __HIP_MEMORY_SCOPE_AGENT);
}

// ---------------------------------------------------------------- prep ------
// Packed: (p*2R, -|p|^2*R); g initialized PRE-SHIFTED: gs = yw.
__global__ __launch_bounds__(256) void prep_kernel(
    const float* __restrict__ x, const float* __restrict__ y,
    float4* __restrict__ px, float4* __restrict__ py, float* __restrict__ g)
{
    int idx = blockIdx.x * 256 + threadIdx.x;
    if (idx >= NB * NPTS) return;
    float x0 = x[idx*3+0], x1 = x[idx*3+1], x2 = x[idx*3+2];
    float xx = fmaf(x0,x0, fmaf(x1,x1, x2*x2));
    px[idx] = make_float4(x0*K_TWO_R, x1*K_TWO_R, x2*K_TWO_R, -xx*K_R);
    float y0 = y[idx*3+0], y1 = y[idx*3+1], y2 = y[idx*3+2];
    float yy = fmaf(y0,y0, fmaf(y1,y1, y2*y2));
    py[idx] = make_float4(y0*K_TWO_R, y1*K_TWO_R, y2*K_TWO_R, -yy*K_R);
    g[idx] = -yy*K_R;   // gs = yw
}

// ------------------------------------------------------- persistent core ----
// Barrier-free segmented pipeline. 256 wgs = 1/CU. Per-wave publish counters
// ctr[b][wg][wave] (bump after vmcnt(0): MALL-serialized, R9-proven). Wave w
// stages segment w (wg w's 128 duals) into a 2-deep LDS buffer + LDS flag;
// consumers sweep segments in rotated order polling LDS flags only.
// Skew bound: staging half-step t+2 transitively requires every wave's
// publish of t => no wave can still be reading buffer parity (t mod 2).
__global__ __launch_bounds__(1024) void sinkhorn_fused(
    const float4* __restrict__ px4, const float4* __restrict__ py4,
    float* __restrict__ f, float* __restrict__ g,
    unsigned* __restrict__ bar, float* __restrict__ out)
{
    __shared__ v2f vyx[1024], vyy[1024], vyz[1024], vyw[1024];  // Y*2R; yw
    __shared__ v2f vxx[1024], vxy[1024], vxz[1024];             // X*2R
    __shared__ v2f vhw2[2048];         // dual planes, 2-deep (parity = t&1)
    __shared__ v2f rowp[1024];         // pre-broadcast row constants
    __shared__ unsigned fl[16];        // per-segment staged-count flags
    __shared__ float wsum[16];

    const int bid  = blockIdx.x;
    const int b    = bid >> 4;
    const int q    = bid & 15;           // wg index within batch
    const int tid  = threadIdx.x;
    const int lane = tid & 63;
    const int wid  = tid >> 6;           // 0..15
    const int row0 = q * 128 + wid * 8;

    const float4* pyb = py4 + b * NPTS;
    const float4* pxb = px4 + b * NPTS;
    float* fb = f + b * NPTS;
    float* gb = g + b * NPTS;
    unsigned* ctrb  = bar + b * 256;       // 16 wg x 16 wave counters
    unsigned* myctr = ctrb + q * 16 + wid;

    // ---- stage SoA planes ----
    #pragma unroll
    for (int i2 = 0; i2 < 2; ++i2) {
        int k = i2 * WGS + tid;
        float4 p = pyb[k];
        ((float*)vyx)[k] = p.x; ((float*)vyy)[k] = p.y;
        ((float*)vyz)[k] = p.z; ((float*)vyw)[k] = p.w;
        float4 q2 = pxb[k];
        ((float*)vxx)[k] = q2.x; ((float*)vxy)[k] = q2.y;
        ((float*)vxz)[k] = q2.z;
    }
    // ---- row constants, pre-broadcast into pairs ----
    {
        int ph  = tid >> 9;
        int w16 = (tid >> 5) & 15;
        int r   = (tid >> 2) & 7;
        int cp  = tid & 3;
        float4 p = (ph ? pyb : pxb)[q * 128 + w16 * 8 + r];
        float v = (cp == 0) ? p.x * K_INV2R :
                  (cp == 1) ? p.y * K_INV2R :
                  (cp == 2) ? p.z * K_INV2R : p.w;
        v2f t; t.x = v; t.y = v;
        rowp[(ph * 16 + w16) * 32 + r * 4 + cp] = t;
    }
    if (tid < 16) fl[tid] = 0;
    __syncthreads();     // the ONLY workgroup barrier in the iteration

    for (int t = 0; t < 100; ++t) {
        const int par = t & 1;
        const float* din = par ? fb : gb;
        float*      dout = par ? gb : fb;
        const v2f* PX = par ? vxx : vyx;
        const v2f* PY = par ? vxy : vyy;
        const v2f* PZ = par ? vxz : vyz;
        v2f* HB = &vhw2[par * 1024];
        const v2f* rp = &rowp[(par * 16 + wid) * 32];

        // ---- stage own segment (seg id = wid, produced by wg wid) ----
        if (t > 0) {
            const unsigned* cl = ctrb + wid * 16;
            for (;;) {
                unsigned v = (lane < 16) ? aloadu(&cl[lane]) : ~0u;
                if (__all((int)(v >= (unsigned)t))) break;
                __builtin_amdgcn_s_sleep(2);
            }
        }
        HB[wid * 64 + lane] = aload2(&din[wid * 128 + 2 * lane]);
        if (lane == 0)
            __hip_atomic_store(&fl[wid], (unsigned)(t + 1),
                               __ATOMIC_RELEASE, __HIP_MEMORY_SCOPE_WORKGROUP);

        // ---- row constants ----
        v2f rx2[8], ry2[8], rz2[8], u02[8];
        #pragma unroll
        for (int r = 0; r < 8; ++r) {
            rx2[r] = rp[r*4+0]; ry2[r] = rp[r*4+1];
            rz2[r] = rp[r*4+2]; u02[r] = rp[r*4+3];
        }
        v2f acc2[8];
        #pragma unroll
        for (int r = 0; r < 8; ++r) { acc2[r].x = 0.f; acc2[r].y = 0.f; }

        // ---- sweep 16 segments, rotated start (own first, no wait) ----
        for (int s = 0; s < 16; ++s) {
            int k = (wid + s) & 15;
            if (s) {
                while (__hip_atomic_load(&fl[k], __ATOMIC_ACQUIRE,
                                         __HIP_MEMORY_SCOPE_WORKGROUP)
                       < (unsigned)(t + 1))
                    __builtin_amdgcn_s_sleep(1);
            }
            int jp = k * 64 + lane;
            v2f X = PX[jp], Y = PY[jp], Z = PZ[jp], H = HB[jp];
            #pragma unroll
            for (int r = 0; r < 8; ++r) {
                v2f w = Z * rz2[r] + (H + u02[r]);
                w = Y * ry2[r] + w;
                w = X * rx2[r] + w;
                v2f e; e.x = fexp2(w.x); e.y = fexp2(w.y);
                acc2[r] += e;
            }
        }

        // ---- reduce + publish + bump own counter ----
        float sv[8];
        #pragma unroll
        for (int r = 0; r < 8; ++r) {
            float s = acc2[r].x + acc2[r].y;
            #pragma unroll
            for (int off = 1; off < 64; off <<= 1)
                s += __shfl_xor(s, off, 64);
            sv[r] = s;
        }
        if (lane < 8) {
            float s = sv[0];
            #pragma unroll
            for (int r = 1; r < 8; ++r) s = (lane == r) ? sv[r] : s;
            float u0s = ((const float*)&rp[lane * 4 + 3])[0];
            astore(&dout[row0 + lane], -11.0f - flog2(s) + u0s);
        }
        asm volatile("s_waitcnt vmcnt(0)" ::: "memory");
        if (lane == 0) astoreu(myctr, (unsigned)(t + 1));
    }

    // ---- EMD: wait all publishes (count 100), duals direct from MALL ----
    for (int k2 = 0; k2 < 16; ++k2) {
        const unsigned* cl = ctrb + k2 * 16;
        for (;;) {
            unsigned v = (lane < 16) ? aloadu(&cl[lane]) : ~0u;
            if (__all((int)(v >= 100u))) break;
            __builtin_amdgcn_s_sleep(2);
        }
    }
    const v2f* rpf = &rowp[wid * 32];   // ph=0 x-rows
    float fR[8];
    #pragma unroll
    for (int r = 0; r < 8; ++r) {
        float xw = ((const float*)&rpf[r * 4 + 3])[0];
        fR[r] = aload(&fb[row0 + r]) - xw;
    }
    {
        v2f rx2[8], ry2[8], rz2[8], u02[8];
        #pragma unroll
        for (int r = 0; r < 8; ++r) {
            rx2[r] = rpf[r*4+0]; ry2[r] = rpf[r*4+1];
            rz2[r] = rpf[r*4+2]; u02[r] = rpf[r*4+3];
        }
        v2f accE; accE.x = 0.f; accE.y = 0.f;
        #pragma unroll 2
        for (int c = 0; c < 16; ++c) {
            int jp = c * 64 + lane;
            v2f H = aload2(&gb[2 * jp]);
            v2f X = vyx[jp], Y = vyy[jp], Z = vyz[jp], YW = vyw[jp];
            #pragma unroll
            for (int r = 0; r < 8; ++r) {
                v2f w = Z * rz2[r] + (H + u02[r]);
                w = Y * ry2[r] + w;
                w = X * rx2[r] + w;
                v2f cr = (H - YW) - w;
                v2f e;
                e.x = fexp2(w.x + fR[r]) * cr.x;
                e.y = fexp2(w.y + fR[r]) * cr.y;
                accE += e;
            }
        }
        float s = accE.x + accE.y;
        #pragma unroll
        for (int off = 1; off < 64; off <<= 1) s += __shfl_xor(s, off, 64);
        if (lane == 0) wsum[wid] = s;
        __syncthreads();
        if (tid == 0) {
            float t2 = 0.f;
            #pragma unroll
            for (int i2 = 0; i2 < 16; ++i2) t2 += wsum[i2];
            atomicAdd(&out[b], t2 * K_EPS_LN2);
        }
    }
}

// -------------------------------------------------------------- launch ------
extern "C" void kernel_launch(void* const* d_in, const int* in_sizes, int n_in,
                              void* d_out, int out_size, void* d_ws, size_t ws_size,
                              hipStream_t stream)
{
    const float* x = (const float*)d_in[0];
    const float* y = (const float*)d_in[1];
    float* out = (float*)d_out;

    char* ws = (char*)d_ws;
    float4*   px  = (float4*)(ws);
    float4*   py  = (float4*)(ws + (size_t)NB * NPTS * 16);
    float*    f   = (float*)  (ws + (size_t)NB * NPTS * 32);
    float*    g   = (float*)  (ws + (size_t)NB * NPTS * 32 + (size_t)NB * NPTS * 4);
    unsigned* bar = (unsigned*)(ws + (size_t)NB * NPTS * 32 + (size_t)NB * NPTS * 8);

    hipMemsetAsync(d_out, 0, (size_t)out_size * sizeof(float), stream);
    hipMemsetAsync(bar, 0, NB * 256 * sizeof(unsigned), stream);

    prep_kernel<<<(NB * NPTS + 255) / 256, 256, 0, stream>>>(x, y, px, py, g);
    sinkhorn_fused<<<NB * 16, WGS, 0, stream>>>(px, py, f, g, bar, out);
}

// Round 16
// 1166.795 us; speedup vs baseline: 1.6476x; 1.1444x over previous
//
#include <hip/hip_runtime.h>

#define NPTS 2048
#define NB   16
#define WGS  1024    // threads per wg (16 waves), 1 wg/CU
#define ARRV 16      // wgs per batch = barrier arrivals

typedef float v2f __attribute__((ext_vector_type(2)));

// eps = 0.01, log-domain Sinkhorn in base-2. Duals stored PRE-SCALED by
// R = 1/(eps*ln2) (log2-units) and PRE-SHIFTED by the owner's plane const:
//   fs_i = fR_i + xw_i,   gs_j = gR_j + yw_j   (xw = -|x|^2 R, yw = -|y|^2 R)
// -log2(2048) = -11 exactly.
constexpr float K_R       = 144.26950408889634f;     // log2(e)/eps
constexpr float K_TWO_R   = 288.53900817779268f;     // 2R
constexpr float K_INV2R   = 0.0034657359027997264f;  // 1/(2R)
constexpr float K_EPS_LN2 = 0.0069314718055994531f;  // 1/R

__device__ __forceinline__ float fexp2(float x) { return __builtin_amdgcn_exp2f(x); }
__device__ __forceinline__ float flog2(float x) { return __builtin_amdgcn_logf(x); }

__device__ __forceinline__ float aload(const float* p) {
    return __hip_atomic_load(p, __ATOMIC_RELAXED, __HIP_MEMORY_SCOPE_AGENT);
}
__device__ __forceinline__ v2f aload2(const float* p) {
    unsigned long long v = __hip_atomic_load((const unsigned long long*)p,
                           __ATOMIC_RELAXED, __HIP_MEMORY_SCOPE_AGENT);
    union { unsigned long long u; v2f f; } c; c.u = v; return c.f;
}
__device__ __forceinline__ void astore(float* p, float v) {
    __hip_atomic_store(p, v, __ATOMIC_RELAXED, __HIP_MEMORY_SCOPE_AGENT);
}

// ---------------------------------------------------------------- prep ------
// Packed: (p*2R, -|p|^2*R); g initialized PRE-SHIFTED: gs = 0 + yw = yw.
__global__ __launch_bounds__(256) void prep_kernel(
    const float* __restrict__ x, const float* __restrict__ y,
    float4* __restrict__ px, float4* __restrict__ py, float* __restrict__ g)
{
    int idx = blockIdx.x * 256 + threadIdx.x;
    if (idx >= NB * NPTS) return;
    float x0 = x[idx*3+0], x1 = x[idx*3+1], x2 = x[idx*3+2];
    float xx = fmaf(x0,x0, fmaf(x1,x1, x2*x2));
    px[idx] = make_float4(x0*K_TWO_R, x1*K_TWO_R, x2*K_TWO_R, -xx*K_R);
    float y0 = y[idx*3+0], y1 = y[idx*3+1], y2 = y[idx*3+2];
    float yy = fmaf(y0,y0, fmaf(y1,y1, y2*y2));
    py[idx] = make_float4(y0*K_TWO_R, y1*K_TWO_R, y2*K_TWO_R, -yy*K_R);
    g[idx] = -yy*K_R;   // gs = yw
}

// --------------------------------------------------------- batch barrier ----
// Fence-free monotonic barrier (R9 protocol, verified absmax 0.0).
__device__ __forceinline__ void batch_barrier(unsigned* ctr, unsigned target) {
    __syncthreads();
    if (threadIdx.x == 0) {
        asm volatile("s_waitcnt vmcnt(0)" ::: "memory");
        __hip_atomic_fetch_add(ctr, 1u, __ATOMIC_RELAXED, __HIP_MEMORY_SCOPE_AGENT);
        while (__hip_atomic_load(ctr, __ATOMIC_RELAXED, __HIP_MEMORY_SCOPE_AGENT)
               < target)
            __builtin_amdgcn_s_sleep(1);
        asm volatile("" ::: "memory");
    }
    __syncthreads();
}

// ------------------------------------------------------- persistent core ----
// 256 wgs = 1/CU (LDS ~74 KB). 16 waves/wg, 8 rows/wave. SoA j-pair planes
// in LDS; packed-f32 inner loop. Staging = pure copy (duals pre-shifted).
__global__ __launch_bounds__(1024) void sinkhorn_fused(
    const float4* __restrict__ px4, const float4* __restrict__ py4,
    float* __restrict__ f, float* __restrict__ g,
    unsigned* __restrict__ bar, float* __restrict__ out)
{
    __shared__ v2f vyx[1024], vyy[1024], vyz[1024], vyw[1024];  // Y*2R; yw (EMD)
    __shared__ v2f vxx[1024], vxy[1024], vxz[1024];             // X*2R
    __shared__ v2f vhw[1024];          // per-phase: staged pre-shifted duals
    __shared__ v2f rowp[1024];         // pre-broadcast row constants
    __shared__ float wsum[16];

    const int bid   = blockIdx.x;
    const int b     = bid >> 4;
    const int chunk = bid & 15;
    const int tid   = threadIdx.x;
    const int lane  = tid & 63;
    const int wid   = tid >> 6;           // 0..15
    const int row0  = chunk * 128 + wid * 8;

    const float4* pyb = py4 + b * NPTS;
    const float4* pxb = px4 + b * NPTS;
    float* fb = f + b * NPTS;
    float* gb = g + b * NPTS;
    unsigned* ctr = bar + b * 64;

    // ---- stage SoA planes (2048 elems, 1024 thr) ----
    #pragma unroll
    for (int i2 = 0; i2 < 2; ++i2) {
        int k = i2 * WGS + tid;
        float4 p = pyb[k];
        ((float*)vyx)[k] = p.x; ((float*)vyy)[k] = p.y;
        ((float*)vyz)[k] = p.z; ((float*)vyw)[k] = p.w;
        float4 q2 = pxb[k];
        ((float*)vxx)[k] = q2.x; ((float*)vxy)[k] = q2.y;
        ((float*)vxz)[k] = q2.z;
    }
    // ---- row constants, pre-broadcast into pairs (1 per thread) ----
    {
        int ph  = tid >> 9;                // 0: f-rows (x), 1: g-rows (y)
        int w16 = (tid >> 5) & 15;
        int r   = (tid >> 2) & 7;
        int cp  = tid & 3;
        float4 p = (ph ? pyb : pxb)[chunk * 128 + w16 * 8 + r];
        float v = (cp == 0) ? p.x * K_INV2R :
                  (cp == 1) ? p.y * K_INV2R :
                  (cp == 2) ? p.z * K_INV2R : p.w;
        v2f t; t.x = v; t.y = v;
        rowp[(ph * 16 + w16) * 32 + r * 4 + cp] = t;
    }

    // dual_out gets PRE-SHIFTED value: -11 - log2(s) + u0_row
    auto run_phase = [&](const v2f* PX, const v2f* PY, const v2f* PZ,
                         int ph, float* dual_out) {
        v2f rx2[8], ry2[8], rz2[8], u02[8];
        const v2f* rp = &rowp[(ph * 16 + wid) * 32];
        #pragma unroll
        for (int r = 0; r < 8; ++r) {
            rx2[r] = rp[r*4+0]; ry2[r] = rp[r*4+1];
            rz2[r] = rp[r*4+2]; u02[r] = rp[r*4+3];
        }
        v2f acc2[8];
        #pragma unroll
        for (int r = 0; r < 8; ++r) { acc2[r].x = 0.f; acc2[r].y = 0.f; }

        #pragma unroll 2
        for (int c = 0; c < 16; ++c) {
            int jp = c * 64 + lane;
            v2f X = PX[jp], Y = PY[jp], Z = PZ[jp], H = vhw[jp];
            #pragma unroll
            for (int r = 0; r < 8; ++r) {
                v2f w = Z * rz2[r] + (H + u02[r]);
                w = Y * ry2[r] + w;
                w = X * rx2[r] + w;
                v2f e; e.x = fexp2(w.x); e.y = fexp2(w.y);
                acc2[r] += e;
            }
        }

        float sv[8];
        #pragma unroll
        for (int r = 0; r < 8; ++r) {
            float s = acc2[r].x + acc2[r].y;
            #pragma unroll
            for (int off = 1; off < 64; off <<= 1)
                s += __shfl_xor(s, off, 64);
            sv[r] = s;
        }
        if (lane < 8) {
            float s = sv[0];
            #pragma unroll
            for (int r = 1; r < 8; ++r) s = (lane == r) ? sv[r] : s;
            float u0s = ((const float*)&rp[lane * 4 + 3])[0];  // LDS re-read
            astore(&dual_out[lane], -11.0f - flog2(s) + u0s);
        }
    };

    unsigned tgt = ARRV;
    for (int it = 0; it < 50; ++it) {
        // ---- f-update: stage gs (pure copy, 1 x 8B per thread) ----
        vhw[tid] = aload2(&gb[2 * tid]);
        __syncthreads();
        run_phase(vyx, vyy, vyz, 0, &fb[row0]);
        batch_barrier(ctr, tgt); tgt += ARRV;

        // ---- g-update: stage fs ----
        vhw[tid] = aload2(&fb[2 * tid]);
        __syncthreads();
        run_phase(vxx, vxy, vxz, 1, &gb[row0]);
        batch_barrier(ctr, tgt); tgt += ARRV;
    }

    // ---- EMD: H = gs;  w = 2Rx.y + gs + xw = gR - CR;  CR = (H-YW) - w;
    //      P = 2^(w + fR),  fR = fs - xw ----
    vhw[tid] = aload2(&gb[2 * tid]);
    const v2f* rpf = &rowp[wid * 32];   // ph=0 x-rows
    float fR[8];
    #pragma unroll
    for (int r = 0; r < 8; ++r) {
        float xw = ((const float*)&rpf[r * 4 + 3])[0];
        fR[r] = aload(&fb[row0 + r]) - xw;
    }
    __syncthreads();

    {
        v2f rx2[8], ry2[8], rz2[8], u02[8];
        #pragma unroll
        for (int r = 0; r < 8; ++r) {
            rx2[r] = rpf[r*4+0]; ry2[r] = rpf[r*4+1];
            rz2[r] = rpf[r*4+2]; u02[r] = rpf[r*4+3];
        }
        v2f accE; accE.x = 0.f; accE.y = 0.f;
        #pragma unroll 2
        for (int c = 0; c < 16; ++c) {
            int jp = c * 64 + lane;
            v2f X = vyx[jp], Y = vyy[jp], Z = vyz[jp];
            v2f H = vhw[jp], YW = vyw[jp];
            #pragma unroll
            for (int r = 0; r < 8; ++r) {
                v2f w = Z * rz2[r] + (H + u02[r]);
                w = Y * ry2[r] + w;
                w = X * rx2[r] + w;
                v2f cr = (H - YW) - w;
                v2f e;
                e.x = fexp2(w.x + fR[r]) * cr.x;
                e.y = fexp2(w.y + fR[r]) * cr.y;
                accE += e;
            }
        }
        float s = accE.x + accE.y;
        #pragma unroll
        for (int off = 1; off < 64; off <<= 1) s += __shfl_xor(s, off, 64);
        if (lane == 0) wsum[wid] = s;
        __syncthreads();
        if (tid == 0) {
            float t = 0.f;
            #pragma unroll
            for (int i2 = 0; i2 < 16; ++i2) t += wsum[i2];
            atomicAdd(&out[b], t * K_EPS_LN2);
        }
    }
}

// -------------------------------------------------------------- launch ------
extern "C" void kernel_launch(void* const* d_in, const int* in_sizes, int n_in,
                              void* d_out, int out_size, void* d_ws, size_t ws_size,
                              hipStream_t stream)
{
    const float* x = (const float*)d_in[0];
    const float* y = (const float*)d_in[1];
    float* out = (float*)d_out;

    char* ws = (char*)d_ws;
    float4*   px  = (float4*)(ws);
    float4*   py  = (float4*)(ws + (size_t)NB * NPTS * 16);
    float*    f   = (float*)  (ws + (size_t)NB * NPTS * 32);
    float*    g   = (float*)  (ws + (size_t)NB * NPTS * 32 + (size_t)NB * NPTS * 4);
    unsigned* bar = (unsigned*)(ws + (size_t)NB * NPTS * 32 + (size_t)NB * NPTS * 8);

    hipMemsetAsync(d_out, 0, (size_t)out_size * sizeof(float), stream);
    hipMemsetAsync(bar, 0, NB * 64 * sizeof(unsigned), stream);

    prep_kernel<<<(NB * NPTS + 255) / 256, 256, 0, stream>>>(x, y, px, py, g);
    sinkhorn_fused<<<NB * ARRV, WGS, 0, stream>>>(px, py, f, g, bar, out);
}